// Round 10
// baseline (757.726 us; speedup 1.0000x reference)
//
#include <hip/hip_runtime.h>

// ---- problem constants ----
static constexpr int kR    = 896;
static constexpr int kLMAX = 510;
static constexpr int kWMAX = 509;
static constexpr int kHID  = 32;
static constexpr int kENC  = 10;
static constexpr int kGH   = 64;
static constexpr int kNCLS = 10;
static constexpr int kB    = 8;
static constexpr int kEPS  = 7168;
static constexpr int kN    = kB * kR;
static constexpr int kE    = kB * kEPS;
static constexpr int kPAD  = 3 * 256 * 256;

// band[r] = 4*i+1, i = ring index within its (m, by, bx) block.
constexpr int band_of(int r) {
    int i = (r < 128) ? r : (r < 384) ? ((r - 128) & 63) : ((r - 384) & 31);
    return 4 * i + 1;
}
__device__ __forceinline__ int band_dev(int r) {
    int i = (r < 128) ? r : (r < 384) ? ((r - 128) & 63) : ((r - 384) & 31);
    return 4 * i + 1;
}

static constexpr int kCHUNK = 128;
constexpr int count_chunks() {
    int n = 0;
    for (int r = 0; r < kR; ++r) n += (band_of(r) + kCHUNK - 1) / kCHUNK;
    return n;
}
static constexpr int kNCHUNK = count_chunks();   // 1216
static_assert(kNCHUNK == 1216, "chunk count");

struct CE { short r; short w0; };
struct Tab { CE e[kNCHUNK]; };
constexpr Tab make_tab() {
    Tab t{};
    int n = 0;
    for (int r = 0; r < kR; ++r)
        for (int w0 = 0; w0 < band_of(r); w0 += kCHUNK) {
            t.e[n].r = (short)r; t.e[n].w0 = (short)w0; ++n;
        }
    return t;
}
__device__ __constant__ Tab g_tab = make_tab();

// ---- workspace layout (floats; ints stored in same region) ----
static constexpr size_t OFF_EMB  = 0;                       // 71680 f
static constexpr size_t OFF_DEG  = OFF_EMB + 71680;         // 7168 f
static constexpr size_t OFF_CNT  = OFF_DEG + 7168;          // 7168 int
static constexpr size_t OFF_POOL = OFF_CNT + 7168;          // 512 f
static constexpr size_t kMEMSET_FLOATS = OFF_POOL + 512;    // zeroed region
static constexpr size_t OFF_DINV = kMEMSET_FLOATS;
static constexpr size_t OFF_CSUM = OFF_DINV + 7168;
static constexpr size_t OFF_OFFS = OFF_CSUM + 7168;         // 7169 int
static constexpr size_t OFF_WOFF = OFF_OFFS + 7169;         // 7169 int
static constexpr size_t OFF_CSRC = OFF_WOFF + 7169;         // 57344 int
static constexpr size_t OFF_CNRM = OFF_CSRC + 57344;        // 57344 f
static constexpr size_t OFF_XW1  = OFF_CNRM + 57344;        // 458752 f
static constexpr size_t OFF_XT   = (OFF_XW1 + 458752 + 7) & ~(size_t)7;  // kPAD*8 f

__device__ __forceinline__ float sigmoidf_(float v) { return 1.0f / (1.0f + expf(-v)); }

// =====================================================================
// Kernel 0: transpose x -> xt[j][b] (float8 per pixel), + edge deg/cnt.
// =====================================================================
__global__ __launch_bounds__(256)
void k_xpose(const float* __restrict__ x, const int* __restrict__ ei,
             const float* __restrict__ edge_w,
             float* __restrict__ xt, float* __restrict__ deg, int* __restrict__ cnt)
{
    const int bid = blockIdx.x;
    const int tid = threadIdx.x;
    if (bid < kPAD / 256) {
        const int j = bid * 256 + tid;
        float4 lo, hi;
        lo.x = x[(size_t)0 * kPAD + j]; lo.y = x[(size_t)1 * kPAD + j];
        lo.z = x[(size_t)2 * kPAD + j]; lo.w = x[(size_t)3 * kPAD + j];
        hi.x = x[(size_t)4 * kPAD + j]; hi.y = x[(size_t)5 * kPAD + j];
        hi.z = x[(size_t)6 * kPAD + j]; hi.w = x[(size_t)7 * kPAD + j];
        float4* dst = (float4*)&xt[(size_t)j * 8];
        dst[0] = lo; dst[1] = hi;
    } else {
        const int e = (bid - kPAD / 256) * 256 + tid;
        if (e < kE) {
            const int t = ei[kE + e];
            atomicAdd(&deg[t], sigmoidf_(edge_w[e % kEPS]));
            atomicAdd(&cnt[t], 1);
        }
    }
}

// =====================================================================
// Kernel 1: band-aware fused conv + decoder. R5 structure (5 waves,
// 2 o-channels/wave), but low-VGPR inner loop: window values re-read
// from LDS per (g,b) instead of cached in 32 registers; Wdec values in
// two static 8-arrays. Target VGPR <= 85 -> 6 waves/SIMD (24 waves/CU).
// All register indexing compile-time (unrolled) -- no scratch.
// =====================================================================
__global__ __launch_bounds__(320, 6)
void k_conv_emb(const float* __restrict__ xt, const int* __restrict__ idx,
                const float* __restrict__ Wconv, const float* __restrict__ bconv,
                const float* __restrict__ Wdec, float* __restrict__ emb)
{
    const int bid = blockIdx.x;
    const int tid = threadIdx.x;

    const int r     = g_tab.e[bid].r;
    const int w0    = g_tab.e[bid].w0;
    const int bandr = band_dev(r);
    const int wc    = min(kCHUNK, bandr - w0);

    __shared__ float vals[2][kB][kCHUNK + 1];
    __shared__ float wconv_s[kHID * 4];
    __shared__ float bconv_s[kHID];

    if (tid < 128) wconv_s[tid] = Wconv[r * 128 + tid];
    else if (tid < 160) bconv_s[tid - 128] = bconv[r * kHID + (tid - 128)];

    if (tid < 2 * (kCHUNK + 1)) {
        const int hh = tid >= (kCHUNK + 1);
        const int li = tid - hh * (kCHUNK + 1);
        const int j = (li <= wc) ? idx[(r * 2 + hh) * kLMAX + w0 + li] : kPAD;
        float4 lo = {0, 0, 0, 0}, hi = {0, 0, 0, 0};
        if ((unsigned)j < (unsigned)kPAD) {
            const float4* src = (const float4*)&xt[(size_t)j * 8];
            lo = src[0]; hi = src[1];
        }
        vals[hh][0][li] = lo.x; vals[hh][1][li] = lo.y;
        vals[hh][2][li] = lo.z; vals[hh][3][li] = lo.w;
        vals[hh][4][li] = hi.x; vals[hh][5][li] = hi.y;
        vals[hh][6][li] = hi.z; vals[hh][7][li] = hi.w;
    }
    __syncthreads();

    const int wave = tid >> 6, lane = tid & 63;
    const int o0 = wave * 2;
    const float* Wd0 = Wdec + ((size_t)(r * kENC + o0) * kHID) * kWMAX;
    const float* Wd1 = Wd0 + (size_t)kHID * kWMAX;

    float acc0[8] = {0,0,0,0,0,0,0,0}, acc1[8] = {0,0,0,0,0,0,0,0};

    #pragma unroll
    for (int st = 0; st < 2; ++st) {
        if (st * 64 >= wc) break;
        const int wl = st * 64 + lane;
        const bool valid = (wl < wc);
        const int w = w0 + wl;

        #pragma unroll
        for (int g = 0; g < 4; ++g) {
            float wd0[8], wd1[8];
            #pragma unroll
            for (int cc = 0; cc < 8; ++cc) {
                wd0[cc] = valid ? Wd0[(size_t)(g * 8 + cc) * kWMAX + w] : 0.0f;
                wd1[cc] = valid ? Wd1[(size_t)(g * 8 + cc) * kWMAX + w] : 0.0f;
            }
            #pragma unroll
            for (int b = 0; b < 8; ++b) {
                const float v00 = vals[0][b][wl], v01 = vals[0][b][wl + 1];
                const float v10 = vals[1][b][wl], v11 = vals[1][b][wl + 1];
                #pragma unroll
                for (int cc = 0; cc < 8; ++cc) {
                    const int c = g * 8 + cc;
                    float h = fmaf(v00, wconv_s[c * 4 + 0], fmaf(v01, wconv_s[c * 4 + 1],
                              fmaf(v10, wconv_s[c * 4 + 2], fmaf(v11, wconv_s[c * 4 + 3],
                                   bconv_s[c]))));
                    h = fmaxf(h, 0.0f);
                    acc0[b] = fmaf(wd0[cc], h, acc0[b]);
                    acc1[b] = fmaf(wd1[cc], h, acc1[b]);
                }
            }
        }
    }

    #pragma unroll
    for (int b = 0; b < 8; ++b) {
        float s0 = acc0[b], s1 = acc1[b];
        #pragma unroll
        for (int sft = 32; sft > 0; sft >>= 1) {
            s0 += __shfl_xor(s0, sft);
            s1 += __shfl_xor(s1, sft);
        }
        if (lane == 0) {
            atomicAdd(&emb[((size_t)b * kR + r) * kENC + o0],     s0);
            atomicAdd(&emb[((size_t)b * kR + r) * kENC + o0 + 1], s1);
        }
    }
}

// =====================================================================
// Kernel 2: block 0 = scan (dinv/colsum init + CSR offsets);
//           blocks 1.. = xw1 = (emb + bdec) @ Wg1.
// =====================================================================
__global__ __launch_bounds__(256)
void k_scanxw1(const float* __restrict__ deg, const int* __restrict__ cnt,
               float* __restrict__ dinv, float* __restrict__ colsum,
               int* __restrict__ off, int* __restrict__ woff,
               const float* __restrict__ emb, const float* __restrict__ bdec,
               const float* __restrict__ Wg1, float* __restrict__ xw1)
{
    const int bid = blockIdx.x;
    const int t = threadIdx.x;
    if (bid > 0) {
        const int tt = (bid - 1) * 256 + t;
        const int i = tt >> 6, f = tt & 63;
        const int r = i % kR;
        float s = 0.0f;
        #pragma unroll
        for (int o = 0; o < kENC; ++o)
            s = fmaf(emb[i * kENC + o] + bdec[r * kENC + o], Wg1[o * kGH + f], s);
        xw1[tt] = s;
        return;
    }

    for (int i = t; i < kN; i += 256) {
        float d = deg[i] + 1.0f;
        dinv[i]   = rsqrtf(d);
        colsum[i] = 1.0f / d;
    }
    __shared__ int cl[kN];
    for (int i = t; i < kN; i += 256) cl[i] = cnt[i];
    __syncthreads();

    int loc[28];
    int s = 0;
    const int base = t * 28;
    #pragma unroll
    for (int k = 0; k < 28; ++k) { loc[k] = s; s += cl[base + k]; }

    __shared__ int sa[256], sb[256];
    sa[t] = s;
    __syncthreads();
    int* in = sa; int* out = sb;
    for (int d = 1; d < 256; d <<= 1) {
        out[t] = in[t] + ((t >= d) ? in[t - d] : 0);
        __syncthreads();
        int* tmp = in; in = out; out = tmp;
    }
    const int incl = in[t];
    const int excl = incl - s;
    #pragma unroll
    for (int k = 0; k < 28; ++k) {
        off[base + k]  = excl + loc[k];
        woff[base + k] = excl + loc[k];
    }
    if (t == 255) off[kN] = incl;
}

// =====================================================================
// Kernel 3: per-edge norm + CSR fill + colsum accumulation.
// =====================================================================
__global__ __launch_bounds__(256)
void k_fill(const int* __restrict__ ei, const float* __restrict__ edge_w,
            const float* __restrict__ dinv, int* __restrict__ woff,
            int* __restrict__ csrc, float* __restrict__ cnrm,
            float* __restrict__ colsum)
{
    int e = blockIdx.x * 256 + threadIdx.x;
    if (e >= kE) return;
    const int s = ei[e], t = ei[kE + e];
    const float nm = dinv[s] * sigmoidf_(edge_w[e % kEPS]) * dinv[t];
    const int p = atomicAdd(&woff[t], 1);
    csrc[p] = s;
    cnrm[p] = nm;
    atomicAdd(&colsum[s], nm);
}

// =====================================================================
// Kernel 4: fused aggregate(layer1) + ReLU + xw2(Wg2 in LDS) + weighted pool.
// =====================================================================
__global__ __launch_bounds__(256)
void k_agg(const float* __restrict__ xw1, const int* __restrict__ off,
           const int* __restrict__ csrc, const float* __restrict__ cnrm,
           const float* __restrict__ dinv, const float* __restrict__ colsum,
           const float* __restrict__ bg1, const float* __restrict__ Wg2,
           float* __restrict__ pooled)
{
    const int tid  = threadIdx.x;
    const int wave = tid >> 6, f = tid & 63;

    __shared__ float wg2s[kGH * kGH];
    __shared__ float hrow[4][kGH];
    __shared__ float pool_s[kGH];

    for (int i = tid; i < kGH * kGH; i += 256) wg2s[i] = Wg2[i];
    if (tid < kGH) pool_s[tid] = 0.0f;
    __syncthreads();

    const int j0 = blockIdx.x * 16;
    #pragma unroll
    for (int q = 0; q < 4; ++q) {
        const int j = j0 + wave * 4 + q;
        const float di = dinv[j];
        float a = fmaf(di * di, xw1[(size_t)j * kGH + f], bg1[f]);
        const int pb = off[j], pe = off[j + 1];
        int   sC = 0; float nC = 0.0f;
        if (pb < pe) { sC = csrc[pb]; nC = cnrm[pb]; }
        for (int p = pb; p < pe; ++p) {
            int sN = sC; float nN = 0.0f;
            if (p + 1 < pe) { sN = csrc[p + 1]; nN = cnrm[p + 1]; }
            a = fmaf(nC, xw1[(size_t)sC * kGH + f], a);
            sC = sN; nC = nN;
        }
        a = fmaxf(a, 0.0f);
        hrow[wave][f] = a;
        float s2 = 0.0f;
        #pragma unroll 8
        for (int f2 = 0; f2 < kGH; ++f2)
            s2 = fmaf(hrow[wave][f2], wg2s[f2 * kGH + f], s2);
        atomicAdd(&pool_s[f], colsum[j] * s2);
    }
    __syncthreads();
    if (tid < kGH) {
        const int b = j0 / kR;
        atomicAdd(&pooled[b * kGH + tid], pool_s[tid]);
    }
}

// =====================================================================
// Kernel 5: head — logits + softmax (tiny).
// =====================================================================
__global__ __launch_bounds__(128)
void k_head(const float* __restrict__ pooled, const float* __restrict__ bg2,
            const float* __restrict__ Wl, const float* __restrict__ bl,
            float* __restrict__ out)
{
    const int t = threadIdx.x;
    __shared__ float lgs[kB * kNCLS];
    if (t < kB * kNCLS) {
        const int b = t / kNCLS, c = t % kNCLS;
        float s = bl[c];
        for (int g = 0; g < kGH; ++g) {
            const float pg = bg2[g] + pooled[b * kGH + g] * (1.0f / kR);
            s = fmaf(pg, Wl[g * kNCLS + c], s);
        }
        lgs[t] = s;
    }
    __syncthreads();
    if (t < kB) {
        float mx = lgs[t * kNCLS];
        for (int j = 1; j < kNCLS; ++j) mx = fmaxf(mx, lgs[t * kNCLS + j]);
        float ssum = 0.0f, ex[kNCLS];
        for (int j = 0; j < kNCLS; ++j) { ex[j] = expf(lgs[t * kNCLS + j] - mx); ssum += ex[j]; }
        for (int j = 0; j < kNCLS; ++j) out[t * kNCLS + j] = ex[j] / ssum;
    }
}

extern "C" void kernel_launch(void* const* d_in, const int* in_sizes, int n_in,
                              void* d_out, int out_size, void* d_ws, size_t ws_size,
                              hipStream_t stream)
{
    const float* x      = (const float*)d_in[0];
    const int*   ei     = (const int*)d_in[1];
    const int*   idx    = (const int*)d_in[3];
    const float* Wconv  = (const float*)d_in[4];
    const float* bconv  = (const float*)d_in[5];
    const float* Wdec   = (const float*)d_in[6];
    const float* bdec   = (const float*)d_in[7];
    const float* edge_w = (const float*)d_in[8];
    const float* Wg1    = (const float*)d_in[9];
    const float* bg1    = (const float*)d_in[10];
    const float* Wg2    = (const float*)d_in[11];
    const float* bg2    = (const float*)d_in[12];
    const float* Wl     = (const float*)d_in[13];
    const float* bl     = (const float*)d_in[14];

    float* ws     = (float*)d_ws;
    float* emb    = ws + OFF_EMB;
    float* deg    = ws + OFF_DEG;
    int*   cnt    = (int*)(ws + OFF_CNT);
    float* pooled = ws + OFF_POOL;
    float* dinv   = ws + OFF_DINV;
    float* colsum = ws + OFF_CSUM;
    int*   off    = (int*)(ws + OFF_OFFS);
    int*   woff   = (int*)(ws + OFF_WOFF);
    int*   csrc   = (int*)(ws + OFF_CSRC);
    float* cnrm   = ws + OFF_CNRM;
    float* xw1    = ws + OFF_XW1;
    float* xt     = ws + OFF_XT;

    hipMemsetAsync(ws, 0, kMEMSET_FLOATS * sizeof(float), stream);

    k_xpose<<<kPAD / 256 + (kE + 255) / 256, 256, 0, stream>>>(x, ei, edge_w, xt, deg, cnt);

    k_conv_emb<<<kNCHUNK, 320, 0, stream>>>(xt, idx, Wconv, bconv, Wdec, emb);

    k_scanxw1<<<1 + kN * kGH / 256, 256, 0, stream>>>(deg, cnt, dinv, colsum, off, woff,
                                                      emb, bdec, Wg1, xw1);
    k_fill<<<(kE + 255) / 256, 256, 0, stream>>>(ei, edge_w, dinv, woff, csrc, cnrm, colsum);
    k_agg <<<kN / 16, 256, 0, stream>>>(xw1, off, csrc, cnrm, dinv, colsum, bg1, Wg2, pooled);
    k_head<<<1, 128, 0, stream>>>(pooled, bg2, Wl, bl, (float*)d_out);
}

// Round 11
// 147.273 us; speedup vs baseline: 5.1450x; 5.1450x over previous
//
#include <hip/hip_runtime.h>

// ---- problem constants ----
static constexpr int kR    = 896;
static constexpr int kLMAX = 510;
static constexpr int kWMAX = 509;
static constexpr int kHID  = 32;
static constexpr int kENC  = 10;
static constexpr int kGH   = 64;
static constexpr int kNCLS = 10;
static constexpr int kB    = 8;
static constexpr int kEPS  = 7168;
static constexpr int kN    = kB * kR;
static constexpr int kE    = kB * kEPS;
static constexpr int kPAD  = 3 * 256 * 256;

// band[r] = 4*i+1, i = ring index within its (m, by, bx) block.
constexpr int band_of(int r) {
    int i = (r < 128) ? r : (r < 384) ? ((r - 128) & 63) : ((r - 384) & 31);
    return 4 * i + 1;
}
__device__ __forceinline__ int band_dev(int r) {
    int i = (r < 128) ? r : (r < 384) ? ((r - 128) & 63) : ((r - 384) & 31);
    return 4 * i + 1;
}

static constexpr int kCHUNK = 128;
constexpr int count_chunks() {
    int n = 0;
    for (int r = 0; r < kR; ++r) n += (band_of(r) + kCHUNK - 1) / kCHUNK;
    return n;
}
static constexpr int kNCHUNK = count_chunks();   // 1216
static_assert(kNCHUNK == 1216, "chunk count");

struct CE { short r; short w0; };
struct Tab { CE e[kNCHUNK]; };
constexpr Tab make_tab() {
    Tab t{};
    int n = 0;
    for (int r = 0; r < kR; ++r)
        for (int w0 = 0; w0 < band_of(r); w0 += kCHUNK) {
            t.e[n].r = (short)r; t.e[n].w0 = (short)w0; ++n;
        }
    return t;
}
__device__ __constant__ Tab g_tab = make_tab();

// ---- workspace layout (floats; ints stored in same region) ----
static constexpr size_t OFF_EMB  = 0;                       // 71680 f
static constexpr size_t OFF_DEG  = OFF_EMB + 71680;         // 7168 f
static constexpr size_t OFF_CNT  = OFF_DEG + 7168;          // 7168 int
static constexpr size_t OFF_POOL = OFF_CNT + 7168;          // 512 f
static constexpr size_t kMEMSET_FLOATS = OFF_POOL + 512;    // zeroed region
static constexpr size_t OFF_DINV = kMEMSET_FLOATS;
static constexpr size_t OFF_CSUM = OFF_DINV + 7168;
static constexpr size_t OFF_OFFS = OFF_CSUM + 7168;         // 7169 int
static constexpr size_t OFF_WOFF = OFF_OFFS + 7169;         // 7169 int
static constexpr size_t OFF_CSRC = OFF_WOFF + 7169;         // 57344 int
static constexpr size_t OFF_CNRM = OFF_CSRC + 57344;        // 57344 f
static constexpr size_t OFF_XW1  = OFF_CNRM + 57344;        // 458752 f
static constexpr size_t OFF_XT   = (OFF_XW1 + 458752 + 7) & ~(size_t)7;  // kPAD*8 f

__device__ __forceinline__ float sigmoidf_(float v) { return 1.0f / (1.0f + expf(-v)); }

// =====================================================================
// Kernel 0: transpose x -> xt[j][b] (float8 per pixel), + edge deg/cnt.
// =====================================================================
__global__ __launch_bounds__(256)
void k_xpose(const float* __restrict__ x, const int* __restrict__ ei,
             const float* __restrict__ edge_w,
             float* __restrict__ xt, float* __restrict__ deg, int* __restrict__ cnt)
{
    const int bid = blockIdx.x;
    const int tid = threadIdx.x;
    if (bid < kPAD / 256) {
        const int j = bid * 256 + tid;
        float4 lo, hi;
        lo.x = x[(size_t)0 * kPAD + j]; lo.y = x[(size_t)1 * kPAD + j];
        lo.z = x[(size_t)2 * kPAD + j]; lo.w = x[(size_t)3 * kPAD + j];
        hi.x = x[(size_t)4 * kPAD + j]; hi.y = x[(size_t)5 * kPAD + j];
        hi.z = x[(size_t)6 * kPAD + j]; hi.w = x[(size_t)7 * kPAD + j];
        float4* dst = (float4*)&xt[(size_t)j * 8];
        dst[0] = lo; dst[1] = hi;
    } else {
        const int e = (bid - kPAD / 256) * 256 + tid;
        if (e < kE) {
            const int t = ei[kE + e];
            atomicAdd(&deg[t], sigmoidf_(edge_w[e % kEPS]));
            atomicAdd(&cnt[t], 1);
        }
    }
}

// =====================================================================
// Kernel 1: band-aware fused conv + decoder.
// 640 threads = 10 waves; wave w owns output channel o = w (ENC = 10).
// Per-wave VGPR naturally low (acc[8] + 32 window regs) -> high occupancy
// WITHOUT launch-bounds caps (R6/R8/R10 lesson: caps => spill).
// All register indexing compile-time.
// =====================================================================
__global__ __launch_bounds__(640)
void k_conv_emb(const float* __restrict__ xt, const int* __restrict__ idx,
                const float* __restrict__ Wconv, const float* __restrict__ bconv,
                const float* __restrict__ Wdec, float* __restrict__ emb)
{
    const int bid = blockIdx.x;
    const int tid = threadIdx.x;

    const int r     = g_tab.e[bid].r;
    const int w0    = g_tab.e[bid].w0;
    const int bandr = band_dev(r);
    const int wc    = min(kCHUNK, bandr - w0);

    __shared__ float vals[2][kB][kCHUNK + 1];
    __shared__ float wconv_s[kHID * 4];
    __shared__ float bconv_s[kHID];

    if (tid < 128) wconv_s[tid] = Wconv[r * 128 + tid];
    else if (tid < 160) bconv_s[tid - 128] = bconv[r * kHID + (tid - 128)];

    if (tid >= 256 && tid < 256 + 2 * (kCHUNK + 1)) {
        const int ii = tid - 256;
        const int hh = ii >= (kCHUNK + 1);
        const int li = ii - hh * (kCHUNK + 1);
        const int j = (li <= wc) ? idx[(r * 2 + hh) * kLMAX + w0 + li] : kPAD;
        float4 lo = {0, 0, 0, 0}, hi = {0, 0, 0, 0};
        if ((unsigned)j < (unsigned)kPAD) {
            const float4* src = (const float4*)&xt[(size_t)j * 8];
            lo = src[0]; hi = src[1];
        }
        vals[hh][0][li] = lo.x; vals[hh][1][li] = lo.y;
        vals[hh][2][li] = lo.z; vals[hh][3][li] = lo.w;
        vals[hh][4][li] = hi.x; vals[hh][5][li] = hi.y;
        vals[hh][6][li] = hi.z; vals[hh][7][li] = hi.w;
    }
    __syncthreads();

    const int wave = tid >> 6, lane = tid & 63;
    const int o = wave;   // 10 waves <-> 10 output channels
    const float* Wd = Wdec + ((size_t)(r * kENC + o) * kHID) * kWMAX;

    float acc[8] = {0,0,0,0,0,0,0,0};

    #pragma unroll
    for (int st = 0; st < 2; ++st) {
        if (st * 64 >= wc) break;
        const int wl = st * 64 + lane;
        const bool valid = (wl < wc);
        const int w = w0 + wl;

        float v00[8], v01[8], v10[8], v11[8];
        #pragma unroll
        for (int b = 0; b < 8; ++b) {
            v00[b] = vals[0][b][wl]; v01[b] = vals[0][b][wl + 1];
            v10[b] = vals[1][b][wl]; v11[b] = vals[1][b][wl + 1];
        }

        #pragma unroll 8
        for (int c = 0; c < kHID; ++c) {
            const float wd = valid ? Wd[(size_t)c * kWMAX + w] : 0.0f;
            const float w00 = wconv_s[c * 4 + 0], w01 = wconv_s[c * 4 + 1];
            const float w10 = wconv_s[c * 4 + 2], w11 = wconv_s[c * 4 + 3];
            const float bc  = bconv_s[c];
            #pragma unroll
            for (int b = 0; b < 8; ++b) {
                float h = fmaf(v00[b], w00, fmaf(v01[b], w01,
                          fmaf(v10[b], w10, fmaf(v11[b], w11, bc))));
                h = fmaxf(h, 0.0f);
                acc[b] = fmaf(wd, h, acc[b]);
            }
        }
    }

    #pragma unroll
    for (int b = 0; b < 8; ++b) {
        float s = acc[b];
        #pragma unroll
        for (int sft = 32; sft > 0; sft >>= 1) s += __shfl_xor(s, sft);
        if (lane == 0) atomicAdd(&emb[((size_t)b * kR + r) * kENC + o], s);
    }
}

// =====================================================================
// Kernel 2: block 0 = scan (dinv/colsum init + CSR offsets);
//           blocks 1.. = xw1 = (emb + bdec) @ Wg1.
// =====================================================================
__global__ __launch_bounds__(256)
void k_scanxw1(const float* __restrict__ deg, const int* __restrict__ cnt,
               float* __restrict__ dinv, float* __restrict__ colsum,
               int* __restrict__ off, int* __restrict__ woff,
               const float* __restrict__ emb, const float* __restrict__ bdec,
               const float* __restrict__ Wg1, float* __restrict__ xw1)
{
    const int bid = blockIdx.x;
    const int t = threadIdx.x;
    if (bid > 0) {
        const int tt = (bid - 1) * 256 + t;
        const int i = tt >> 6, f = tt & 63;
        const int r = i % kR;
        float s = 0.0f;
        #pragma unroll
        for (int o = 0; o < kENC; ++o)
            s = fmaf(emb[i * kENC + o] + bdec[r * kENC + o], Wg1[o * kGH + f], s);
        xw1[tt] = s;
        return;
    }

    for (int i = t; i < kN; i += 256) {
        float d = deg[i] + 1.0f;
        dinv[i]   = rsqrtf(d);
        colsum[i] = 1.0f / d;
    }
    __shared__ int cl[kN];
    for (int i = t; i < kN; i += 256) cl[i] = cnt[i];
    __syncthreads();

    int loc[28];
    int s = 0;
    const int base = t * 28;
    #pragma unroll
    for (int k = 0; k < 28; ++k) { loc[k] = s; s += cl[base + k]; }

    __shared__ int sa[256], sb[256];
    sa[t] = s;
    __syncthreads();
    int* in = sa; int* out = sb;
    for (int d = 1; d < 256; d <<= 1) {
        out[t] = in[t] + ((t >= d) ? in[t - d] : 0);
        __syncthreads();
        int* tmp = in; in = out; out = tmp;
    }
    const int incl = in[t];
    const int excl = incl - s;
    #pragma unroll
    for (int k = 0; k < 28; ++k) {
        off[base + k]  = excl + loc[k];
        woff[base + k] = excl + loc[k];
    }
    if (t == 255) off[kN] = incl;
}

// =====================================================================
// Kernel 3: per-edge norm + CSR fill + colsum accumulation.
// =====================================================================
__global__ __launch_bounds__(256)
void k_fill(const int* __restrict__ ei, const float* __restrict__ edge_w,
            const float* __restrict__ dinv, int* __restrict__ woff,
            int* __restrict__ csrc, float* __restrict__ cnrm,
            float* __restrict__ colsum)
{
    int e = blockIdx.x * 256 + threadIdx.x;
    if (e >= kE) return;
    const int s = ei[e], t = ei[kE + e];
    const float nm = dinv[s] * sigmoidf_(edge_w[e % kEPS]) * dinv[t];
    const int p = atomicAdd(&woff[t], 1);
    csrc[p] = s;
    cnrm[p] = nm;
    atomicAdd(&colsum[s], nm);
}

// =====================================================================
// Kernel 4: fused aggregate(layer1) + ReLU + xw2(Wg2 in LDS) + weighted pool.
// =====================================================================
__global__ __launch_bounds__(256)
void k_agg(const float* __restrict__ xw1, const int* __restrict__ off,
           const int* __restrict__ csrc, const float* __restrict__ cnrm,
           const float* __restrict__ dinv, const float* __restrict__ colsum,
           const float* __restrict__ bg1, const float* __restrict__ Wg2,
           float* __restrict__ pooled)
{
    const int tid  = threadIdx.x;
    const int wave = tid >> 6, f = tid & 63;

    __shared__ float wg2s[kGH * kGH];
    __shared__ float hrow[4][kGH];
    __shared__ float pool_s[kGH];

    for (int i = tid; i < kGH * kGH; i += 256) wg2s[i] = Wg2[i];
    if (tid < kGH) pool_s[tid] = 0.0f;
    __syncthreads();

    const int j0 = blockIdx.x * 16;
    #pragma unroll
    for (int q = 0; q < 4; ++q) {
        const int j = j0 + wave * 4 + q;
        const float di = dinv[j];
        float a = fmaf(di * di, xw1[(size_t)j * kGH + f], bg1[f]);
        const int pb = off[j], pe = off[j + 1];
        int   sC = 0; float nC = 0.0f;
        if (pb < pe) { sC = csrc[pb]; nC = cnrm[pb]; }
        for (int p = pb; p < pe; ++p) {
            int sN = sC; float nN = 0.0f;
            if (p + 1 < pe) { sN = csrc[p + 1]; nN = cnrm[p + 1]; }
            a = fmaf(nC, xw1[(size_t)sC * kGH + f], a);
            sC = sN; nC = nN;
        }
        a = fmaxf(a, 0.0f);
        hrow[wave][f] = a;
        float s2 = 0.0f;
        #pragma unroll 8
        for (int f2 = 0; f2 < kGH; ++f2)
            s2 = fmaf(hrow[wave][f2], wg2s[f2 * kGH + f], s2);
        atomicAdd(&pool_s[f], colsum[j] * s2);
    }
    __syncthreads();
    if (tid < kGH) {
        const int b = j0 / kR;
        atomicAdd(&pooled[b * kGH + tid], pool_s[tid]);
    }
}

// =====================================================================
// Kernel 5: head — logits + softmax (tiny).
// =====================================================================
__global__ __launch_bounds__(128)
void k_head(const float* __restrict__ pooled, const float* __restrict__ bg2,
            const float* __restrict__ Wl, const float* __restrict__ bl,
            float* __restrict__ out)
{
    const int t = threadIdx.x;
    __shared__ float lgs[kB * kNCLS];
    if (t < kB * kNCLS) {
        const int b = t / kNCLS, c = t % kNCLS;
        float s = bl[c];
        for (int g = 0; g < kGH; ++g) {
            const float pg = bg2[g] + pooled[b * kGH + g] * (1.0f / kR);
            s = fmaf(pg, Wl[g * kNCLS + c], s);
        }
        lgs[t] = s;
    }
    __syncthreads();
    if (t < kB) {
        float mx = lgs[t * kNCLS];
        for (int j = 1; j < kNCLS; ++j) mx = fmaxf(mx, lgs[t * kNCLS + j]);
        float ssum = 0.0f, ex[kNCLS];
        for (int j = 0; j < kNCLS; ++j) { ex[j] = expf(lgs[t * kNCLS + j] - mx); ssum += ex[j]; }
        for (int j = 0; j < kNCLS; ++j) out[t * kNCLS + j] = ex[j] / ssum;
    }
}

extern "C" void kernel_launch(void* const* d_in, const int* in_sizes, int n_in,
                              void* d_out, int out_size, void* d_ws, size_t ws_size,
                              hipStream_t stream)
{
    const float* x      = (const float*)d_in[0];
    const int*   ei     = (const int*)d_in[1];
    const int*   idx    = (const int*)d_in[3];
    const float* Wconv  = (const float*)d_in[4];
    const float* bconv  = (const float*)d_in[5];
    const float* Wdec   = (const float*)d_in[6];
    const float* bdec   = (const float*)d_in[7];
    const float* edge_w = (const float*)d_in[8];
    const float* Wg1    = (const float*)d_in[9];
    const float* bg1    = (const float*)d_in[10];
    const float* Wg2    = (const float*)d_in[11];
    const float* bg2    = (const float*)d_in[12];
    const float* Wl     = (const float*)d_in[13];
    const float* bl     = (const float*)d_in[14];

    float* ws     = (float*)d_ws;
    float* emb    = ws + OFF_EMB;
    float* deg    = ws + OFF_DEG;
    int*   cnt    = (int*)(ws + OFF_CNT);
    float* pooled = ws + OFF_POOL;
    float* dinv   = ws + OFF_DINV;
    float* colsum = ws + OFF_CSUM;
    int*   off    = (int*)(ws + OFF_OFFS);
    int*   woff   = (int*)(ws + OFF_WOFF);
    int*   csrc   = (int*)(ws + OFF_CSRC);
    float* cnrm   = ws + OFF_CNRM;
    float* xw1    = ws + OFF_XW1;
    float* xt     = ws + OFF_XT;

    hipMemsetAsync(ws, 0, kMEMSET_FLOATS * sizeof(float), stream);

    k_xpose<<<kPAD / 256 + (kE + 255) / 256, 256, 0, stream>>>(x, ei, edge_w, xt, deg, cnt);

    k_conv_emb<<<kNCHUNK, 640, 0, stream>>>(xt, idx, Wconv, bconv, Wdec, emb);

    k_scanxw1<<<1 + kN * kGH / 256, 256, 0, stream>>>(deg, cnt, dinv, colsum, off, woff,
                                                      emb, bdec, Wg1, xw1);
    k_fill<<<(kE + 255) / 256, 256, 0, stream>>>(ei, edge_w, dinv, woff, csrc, cnrm, colsum);
    k_agg <<<kN / 16, 256, 0, stream>>>(xw1, off, csrc, cnrm, dinv, colsum, bg1, Wg2, pooled);
    k_head<<<1, 128, 0, stream>>>(pooled, bg2, Wl, bl, (float*)d_out);
}

// Round 12
// 121.234 us; speedup vs baseline: 6.2501x; 1.2148x over previous
//
#include <hip/hip_runtime.h>

// ---- problem constants ----
static constexpr int kR    = 896;
static constexpr int kLMAX = 510;
static constexpr int kWMAX = 509;
static constexpr int kHID  = 32;
static constexpr int kENC  = 10;
static constexpr int kGH   = 64;
static constexpr int kNCLS = 10;
static constexpr int kB    = 8;
static constexpr int kEPS  = 7168;
static constexpr int kN    = kB * kR;
static constexpr int kE    = kB * kEPS;
static constexpr int kPAD  = 3 * 256 * 256;

// band[r] = 4*i+1, i = ring index within its (m, by, bx) block.
constexpr int band_of(int r) {
    int i = (r < 128) ? r : (r < 384) ? ((r - 128) & 63) : ((r - 384) & 31);
    return 4 * i + 1;
}
__device__ __forceinline__ int band_dev(int r) {
    int i = (r < 128) ? r : (r < 384) ? ((r - 128) & 63) : ((r - 384) & 31);
    return 4 * i + 1;
}

static constexpr int kCHUNK = 256;   // R12: 128 -> 256 (1 KB runs per row)
constexpr int count_chunks() {
    int n = 0;
    for (int r = 0; r < kR; ++r) n += (band_of(r) + kCHUNK - 1) / kCHUNK;
    return n;
}
static constexpr int kNCHUNK = count_chunks();   // 960
static_assert(kNCHUNK == 960, "chunk count");

struct CE { short r; short w0; };
struct Tab { CE e[kNCHUNK]; };
// Two-pass generation: wide chunks (wc >= 128) first -> big blocks scheduled early.
constexpr Tab make_tab() {
    Tab t{};
    int n = 0;
    for (int pass = 0; pass < 2; ++pass) {
        for (int r = 0; r < kR; ++r) {
            const int bnd = band_of(r);
            for (int w0 = 0; w0 < bnd; w0 += kCHUNK) {
                int wc = bnd - w0; if (wc > kCHUNK) wc = kCHUNK;
                const bool wide = (wc >= 128);
                if ((pass == 0) == wide) { t.e[n].r = (short)r; t.e[n].w0 = (short)w0; ++n; }
            }
        }
    }
    return t;
}
__device__ __constant__ Tab g_tab = make_tab();

// ---- workspace layout (floats; ints stored in same region) ----
static constexpr size_t OFF_EMB  = 0;                       // 71680 f
static constexpr size_t OFF_DEG  = OFF_EMB + 71680;         // 7168 f
static constexpr size_t OFF_CNT  = OFF_DEG + 7168;          // 7168 int
static constexpr size_t OFF_POOL = OFF_CNT + 7168;          // 512 f
static constexpr size_t kMEMSET_FLOATS = OFF_POOL + 512;    // zeroed region
static constexpr size_t OFF_DINV = kMEMSET_FLOATS;
static constexpr size_t OFF_CSUM = OFF_DINV + 7168;
static constexpr size_t OFF_OFFS = OFF_CSUM + 7168;         // 7169 int
static constexpr size_t OFF_WOFF = OFF_OFFS + 7169;         // 7169 int
static constexpr size_t OFF_CSRC = OFF_WOFF + 7169;         // 57344 int
static constexpr size_t OFF_CNRM = OFF_CSRC + 57344;        // 57344 f
static constexpr size_t OFF_XW1  = OFF_CNRM + 57344;        // 458752 f
static constexpr size_t OFF_XT   = (OFF_XW1 + 458752 + 7) & ~(size_t)7;  // kPAD*8 f

__device__ __forceinline__ float sigmoidf_(float v) { return 1.0f / (1.0f + expf(-v)); }

// =====================================================================
// Kernel 0: transpose x -> xt[j][b] (float8 per pixel), + edge deg/cnt.
// =====================================================================
__global__ __launch_bounds__(256)
void k_xpose(const float* __restrict__ x, const int* __restrict__ ei,
             const float* __restrict__ edge_w,
             float* __restrict__ xt, float* __restrict__ deg, int* __restrict__ cnt)
{
    const int bid = blockIdx.x;
    const int tid = threadIdx.x;
    if (bid < kPAD / 256) {
        const int j = bid * 256 + tid;
        float4 lo, hi;
        lo.x = x[(size_t)0 * kPAD + j]; lo.y = x[(size_t)1 * kPAD + j];
        lo.z = x[(size_t)2 * kPAD + j]; lo.w = x[(size_t)3 * kPAD + j];
        hi.x = x[(size_t)4 * kPAD + j]; hi.y = x[(size_t)5 * kPAD + j];
        hi.z = x[(size_t)6 * kPAD + j]; hi.w = x[(size_t)7 * kPAD + j];
        float4* dst = (float4*)&xt[(size_t)j * 8];
        dst[0] = lo; dst[1] = hi;
    } else {
        const int e = (bid - kPAD / 256) * 256 + tid;
        if (e < kE) {
            const int t = ei[kE + e];
            atomicAdd(&deg[t], sigmoidf_(edge_w[e % kEPS]));
            atomicAdd(&cnt[t], 1);
        }
    }
}

// =====================================================================
// Kernel 1: band-aware fused conv + decoder. R5 structure (5 waves,
// 2 o-channels/wave, direct loads, immediate consume), kCHUNK=256.
// No min-waves launch-bound cap (R6/R8/R10: caps => spill).
// =====================================================================
__global__ __launch_bounds__(320)
void k_conv_emb(const float* __restrict__ xt, const int* __restrict__ idx,
                const float* __restrict__ Wconv, const float* __restrict__ bconv,
                const float* __restrict__ Wdec, float* __restrict__ emb)
{
    const int bid = blockIdx.x;
    const int tid = threadIdx.x;

    const int r     = g_tab.e[bid].r;
    const int w0    = g_tab.e[bid].w0;
    const int bandr = band_dev(r);
    const int wc    = min(kCHUNK, bandr - w0);

    __shared__ float vals[2][kB][kCHUNK + 1];   // 16.4 KB
    __shared__ float wconv_s[kHID * 4];
    __shared__ float bconv_s[kHID];

    if (tid < 128) wconv_s[tid] = Wconv[r * 128 + tid];
    else if (tid < 160) bconv_s[tid - 128] = bconv[r * kHID + (tid - 128)];

    for (int i = tid; i < 2 * (kCHUNK + 1); i += 320) {
        const int hh = i >= (kCHUNK + 1);
        const int li = i - hh * (kCHUNK + 1);
        const int j = (li <= wc) ? idx[(r * 2 + hh) * kLMAX + w0 + li] : kPAD;
        float4 lo = {0, 0, 0, 0}, hi = {0, 0, 0, 0};
        if ((unsigned)j < (unsigned)kPAD) {
            const float4* src = (const float4*)&xt[(size_t)j * 8];
            lo = src[0]; hi = src[1];
        }
        vals[hh][0][li] = lo.x; vals[hh][1][li] = lo.y;
        vals[hh][2][li] = lo.z; vals[hh][3][li] = lo.w;
        vals[hh][4][li] = hi.x; vals[hh][5][li] = hi.y;
        vals[hh][6][li] = hi.z; vals[hh][7][li] = hi.w;
    }
    __syncthreads();

    const int wave = tid >> 6, lane = tid & 63;
    const int o0 = wave * 2;
    const float* Wd0 = Wdec + ((size_t)(r * kENC + o0) * kHID) * kWMAX;
    const float* Wd1 = Wd0 + (size_t)kHID * kWMAX;

    float acc0[8] = {0,0,0,0,0,0,0,0}, acc1[8] = {0,0,0,0,0,0,0,0};

    #pragma unroll 1
    for (int st = 0; st < kCHUNK / 64; ++st) {
        if (st * 64 >= wc) break;
        const int wl = st * 64 + lane;
        const bool valid = (wl < wc);
        const int w = w0 + wl;

        float v00[8], v01[8], v10[8], v11[8];
        #pragma unroll
        for (int b = 0; b < 8; ++b) {
            v00[b] = vals[0][b][wl]; v01[b] = vals[0][b][wl + 1];
            v10[b] = vals[1][b][wl]; v11[b] = vals[1][b][wl + 1];
        }

        #pragma unroll 8
        for (int c = 0; c < kHID; ++c) {
            const float wd0 = valid ? Wd0[(size_t)c * kWMAX + w] : 0.0f;
            const float wd1 = valid ? Wd1[(size_t)c * kWMAX + w] : 0.0f;
            const float w00 = wconv_s[c * 4 + 0], w01 = wconv_s[c * 4 + 1];
            const float w10 = wconv_s[c * 4 + 2], w11 = wconv_s[c * 4 + 3];
            const float bc  = bconv_s[c];
            #pragma unroll
            for (int b = 0; b < 8; ++b) {
                float h = fmaf(v00[b], w00, fmaf(v01[b], w01,
                          fmaf(v10[b], w10, fmaf(v11[b], w11, bc))));
                h = fmaxf(h, 0.0f);
                acc0[b] = fmaf(wd0, h, acc0[b]);
                acc1[b] = fmaf(wd1, h, acc1[b]);
            }
        }
    }

    #pragma unroll
    for (int b = 0; b < 8; ++b) {
        float s0 = acc0[b], s1 = acc1[b];
        #pragma unroll
        for (int sft = 32; sft > 0; sft >>= 1) {
            s0 += __shfl_xor(s0, sft);
            s1 += __shfl_xor(s1, sft);
        }
        if (lane == 0) {
            atomicAdd(&emb[((size_t)b * kR + r) * kENC + o0],     s0);
            atomicAdd(&emb[((size_t)b * kR + r) * kENC + o0 + 1], s1);
        }
    }
}

// =====================================================================
// Kernel 2: block 0 = scan (dinv/colsum init + CSR offsets);
//           blocks 1.. = xw1 = (emb + bdec) @ Wg1.
// =====================================================================
__global__ __launch_bounds__(256)
void k_scanxw1(const float* __restrict__ deg, const int* __restrict__ cnt,
               float* __restrict__ dinv, float* __restrict__ colsum,
               int* __restrict__ off, int* __restrict__ woff,
               const float* __restrict__ emb, const float* __restrict__ bdec,
               const float* __restrict__ Wg1, float* __restrict__ xw1)
{
    const int bid = blockIdx.x;
    const int t = threadIdx.x;
    if (bid > 0) {
        const int tt = (bid - 1) * 256 + t;
        const int i = tt >> 6, f = tt & 63;
        const int r = i % kR;
        float s = 0.0f;
        #pragma unroll
        for (int o = 0; o < kENC; ++o)
            s = fmaf(emb[i * kENC + o] + bdec[r * kENC + o], Wg1[o * kGH + f], s);
        xw1[tt] = s;
        return;
    }

    for (int i = t; i < kN; i += 256) {
        float d = deg[i] + 1.0f;
        dinv[i]   = rsqrtf(d);
        colsum[i] = 1.0f / d;
    }
    __shared__ int cl[kN];
    for (int i = t; i < kN; i += 256) cl[i] = cnt[i];
    __syncthreads();

    int loc[28];
    int s = 0;
    const int base = t * 28;
    #pragma unroll
    for (int k = 0; k < 28; ++k) { loc[k] = s; s += cl[base + k]; }

    __shared__ int sa[256], sb[256];
    sa[t] = s;
    __syncthreads();
    int* in = sa; int* out = sb;
    for (int d = 1; d < 256; d <<= 1) {
        out[t] = in[t] + ((t >= d) ? in[t - d] : 0);
        __syncthreads();
        int* tmp = in; in = out; out = tmp;
    }
    const int incl = in[t];
    const int excl = incl - s;
    #pragma unroll
    for (int k = 0; k < 28; ++k) {
        off[base + k]  = excl + loc[k];
        woff[base + k] = excl + loc[k];
    }
    if (t == 255) off[kN] = incl;
}

// =====================================================================
// Kernel 3: per-edge norm + CSR fill + colsum accumulation.
// =====================================================================
__global__ __launch_bounds__(256)
void k_fill(const int* __restrict__ ei, const float* __restrict__ edge_w,
            const float* __restrict__ dinv, int* __restrict__ woff,
            int* __restrict__ csrc, float* __restrict__ cnrm,
            float* __restrict__ colsum)
{
    int e = blockIdx.x * 256 + threadIdx.x;
    if (e >= kE) return;
    const int s = ei[e], t = ei[kE + e];
    const float nm = dinv[s] * sigmoidf_(edge_w[e % kEPS]) * dinv[t];
    const int p = atomicAdd(&woff[t], 1);
    csrc[p] = s;
    cnrm[p] = nm;
    atomicAdd(&colsum[s], nm);
}

// =====================================================================
// Kernel 4: fused aggregate(layer1) + ReLU + xw2(Wg2 in LDS) + weighted pool.
// =====================================================================
__global__ __launch_bounds__(256)
void k_agg(const float* __restrict__ xw1, const int* __restrict__ off,
           const int* __restrict__ csrc, const float* __restrict__ cnrm,
           const float* __restrict__ dinv, const float* __restrict__ colsum,
           const float* __restrict__ bg1, const float* __restrict__ Wg2,
           float* __restrict__ pooled)
{
    const int tid  = threadIdx.x;
    const int wave = tid >> 6, f = tid & 63;

    __shared__ float wg2s[kGH * kGH];
    __shared__ float hrow[4][kGH];
    __shared__ float pool_s[kGH];

    for (int i = tid; i < kGH * kGH; i += 256) wg2s[i] = Wg2[i];
    if (tid < kGH) pool_s[tid] = 0.0f;
    __syncthreads();

    const int j0 = blockIdx.x * 16;
    #pragma unroll
    for (int q = 0; q < 4; ++q) {
        const int j = j0 + wave * 4 + q;
        const float di = dinv[j];
        float a = fmaf(di * di, xw1[(size_t)j * kGH + f], bg1[f]);
        const int pb = off[j], pe = off[j + 1];
        int   sC = 0; float nC = 0.0f;
        if (pb < pe) { sC = csrc[pb]; nC = cnrm[pb]; }
        for (int p = pb; p < pe; ++p) {
            int sN = sC; float nN = 0.0f;
            if (p + 1 < pe) { sN = csrc[p + 1]; nN = cnrm[p + 1]; }
            a = fmaf(nC, xw1[(size_t)sC * kGH + f], a);
            sC = sN; nC = nN;
        }
        a = fmaxf(a, 0.0f);
        hrow[wave][f] = a;
        float s2 = 0.0f;
        #pragma unroll 8
        for (int f2 = 0; f2 < kGH; ++f2)
            s2 = fmaf(hrow[wave][f2], wg2s[f2 * kGH + f], s2);
        atomicAdd(&pool_s[f], colsum[j] * s2);
    }
    __syncthreads();
    if (tid < kGH) {
        const int b = j0 / kR;
        atomicAdd(&pooled[b * kGH + tid], pool_s[tid]);
    }
}

// =====================================================================
// Kernel 5: head — logits + softmax (tiny).
// =====================================================================
__global__ __launch_bounds__(128)
void k_head(const float* __restrict__ pooled, const float* __restrict__ bg2,
            const float* __restrict__ Wl, const float* __restrict__ bl,
            float* __restrict__ out)
{
    const int t = threadIdx.x;
    __shared__ float lgs[kB * kNCLS];
    if (t < kB * kNCLS) {
        const int b = t / kNCLS, c = t % kNCLS;
        float s = bl[c];
        for (int g = 0; g < kGH; ++g) {
            const float pg = bg2[g] + pooled[b * kGH + g] * (1.0f / kR);
            s = fmaf(pg, Wl[g * kNCLS + c], s);
        }
        lgs[t] = s;
    }
    __syncthreads();
    if (t < kB) {
        float mx = lgs[t * kNCLS];
        for (int j = 1; j < kNCLS; ++j) mx = fmaxf(mx, lgs[t * kNCLS + j]);
        float ssum = 0.0f, ex[kNCLS];
        for (int j = 0; j < kNCLS; ++j) { ex[j] = expf(lgs[t * kNCLS + j] - mx); ssum += ex[j]; }
        for (int j = 0; j < kNCLS; ++j) out[t * kNCLS + j] = ex[j] / ssum;
    }
}

extern "C" void kernel_launch(void* const* d_in, const int* in_sizes, int n_in,
                              void* d_out, int out_size, void* d_ws, size_t ws_size,
                              hipStream_t stream)
{
    const float* x      = (const float*)d_in[0];
    const int*   ei     = (const int*)d_in[1];
    const int*   idx    = (const int*)d_in[3];
    const float* Wconv  = (const float*)d_in[4];
    const float* bconv  = (const float*)d_in[5];
    const float* Wdec   = (const float*)d_in[6];
    const float* bdec   = (const float*)d_in[7];
    const float* edge_w = (const float*)d_in[8];
    const float* Wg1    = (const float*)d_in[9];
    const float* bg1    = (const float*)d_in[10];
    const float* Wg2    = (const float*)d_in[11];
    const float* bg2    = (const float*)d_in[12];
    const float* Wl     = (const float*)d_in[13];
    const float* bl     = (const float*)d_in[14];

    float* ws     = (float*)d_ws;
    float* emb    = ws + OFF_EMB;
    float* deg    = ws + OFF_DEG;
    int*   cnt    = (int*)(ws + OFF_CNT);
    float* pooled = ws + OFF_POOL;
    float* dinv   = ws + OFF_DINV;
    float* colsum = ws + OFF_CSUM;
    int*   off    = (int*)(ws + OFF_OFFS);
    int*   woff   = (int*)(ws + OFF_WOFF);
    int*   csrc   = (int*)(ws + OFF_CSRC);
    float* cnrm   = ws + OFF_CNRM;
    float* xw1    = ws + OFF_XW1;
    float* xt     = ws + OFF_XT;

    hipMemsetAsync(ws, 0, kMEMSET_FLOATS * sizeof(float), stream);

    k_xpose<<<kPAD / 256 + (kE + 255) / 256, 256, 0, stream>>>(x, ei, edge_w, xt, deg, cnt);

    k_conv_emb<<<kNCHUNK, 320, 0, stream>>>(xt, idx, Wconv, bconv, Wdec, emb);

    k_scanxw1<<<1 + kN * kGH / 256, 256, 0, stream>>>(deg, cnt, dinv, colsum, off, woff,
                                                      emb, bdec, Wg1, xw1);
    k_fill<<<(kE + 255) / 256, 256, 0, stream>>>(ei, edge_w, dinv, woff, csrc, cnrm, colsum);
    k_agg <<<kN / 16, 256, 0, stream>>>(xw1, off, csrc, cnrm, dinv, colsum, bg1, Wg2, pooled);
    k_head<<<1, 128, 0, stream>>>(pooled, bg2, Wl, bl, (float*)d_out);
}